// Round 2
// baseline (190.869 us; speedup 1.0000x reference)
//
#include <hip/hip_runtime.h>
#include <math.h>

// Problem constants (from reference setup_inputs)
#define BB 2
#define CC 32
#define HH 128
#define WW 160
#define DD 32
#define NN 4
#define HW (HH * WW)        // 20480
#define GG 8

typedef float v2f __attribute__((ext_vector_type(2)));

// ---------------------------------------------------------------------------
// Device helper: per-(b,src) projection matrices (FP64 Gauss-Jordan).
// Runs on threads 0..7 of prep block (0,0); round-1 showed isolating it in
// its own kernel buys nothing (theory falsified), so it lives here again.
// ---------------------------------------------------------------------------
__device__ void compute_mats(int t, const float* __restrict__ proj,
                             float* __restrict__ mats) {
    int b = t >> 2, n = t & 3;
    const float* Er = proj + ((size_t)(b * (NN + 1) + 0) * 2 + 0) * 16;
    const float* Kr = proj + ((size_t)(b * (NN + 1) + 0) * 2 + 1) * 16;
    const float* Es = proj + ((size_t)(b * (NN + 1) + n + 1) * 2 + 0) * 16;
    const float* Ks = proj + ((size_t)(b * (NN + 1) + n + 1) * 2 + 1) * 16;

    double A[4][4], Bm[4][4];
    for (int r = 0; r < 4; r++)
        for (int c = 0; c < 4; c++) {
            if (r < 3) {
                A[r][c]  = (double)Kr[r*4+0]*Er[0*4+c] + (double)Kr[r*4+1]*Er[1*4+c] + (double)Kr[r*4+2]*Er[2*4+c];
                Bm[r][c] = (double)Ks[r*4+0]*Es[0*4+c] + (double)Ks[r*4+1]*Es[1*4+c] + (double)Ks[r*4+2]*Es[2*4+c];
            } else {
                A[r][c]  = (double)Er[12 + c];
                Bm[r][c] = (double)Es[12 + c];
            }
        }
    double M[4][8];
    for (int i = 0; i < 4; i++)
        for (int j = 0; j < 4; j++) { M[i][j] = A[i][j]; M[i][4+j] = (i == j) ? 1.0 : 0.0; }
    for (int col = 0; col < 4; col++) {
        int piv = col;
        for (int r = col + 1; r < 4; r++)
            if (fabs(M[r][col]) > fabs(M[piv][col])) piv = r;
        if (piv != col)
            for (int j = 0; j < 8; j++) { double tmp = M[col][j]; M[col][j] = M[piv][j]; M[piv][j] = tmp; }
        double pv = M[col][col];
        for (int j = 0; j < 8; j++) M[col][j] /= pv;
        for (int r = 0; r < 4; r++) {
            if (r == col) continue;
            double f = M[r][col];
            for (int j = 0; j < 8; j++) M[r][j] -= f * M[col][j];
        }
    }
    float* o = mats + t * 12;
    for (int i = 0; i < 3; i++) {
        double p0 = 0, p1 = 0, p2 = 0, p3 = 0;
        for (int k = 0; k < 4; k++) {
            p0 += Bm[i][k] * M[k][4+0];
            p1 += Bm[i][k] * M[k][4+1];
            p2 += Bm[i][k] * M[k][4+2];
            p3 += Bm[i][k] * M[k][4+3];
        }
        o[i*3+0] = (float)p0; o[i*3+1] = (float)p1; o[i*3+2] = (float)p2;
        o[9 + i] = (float)p3;
    }
}

// ---------------------------------------------------------------------------
// Kernel 1: direct transpose [32][HW] -> [HW][32]; slabs 0-7 = src, 8-9 = ref.
// No LDS, no barrier: each thread reads 4 channel-strided scalars (coalesced
// in 32B segments per 8-lane group) and writes one coalesced float4.
// 4 hw-tiles per block, fully unrolled -> 16 loads in flight.
// ---------------------------------------------------------------------------
__global__ __launch_bounds__(256) void prep_transpose(const float* __restrict__ src,
                                                      const float* __restrict__ ref,
                                                      const float* __restrict__ proj,
                                                      float* __restrict__ srcT,
                                                      float* __restrict__ refT,
                                                      float* __restrict__ mats) {
    if (blockIdx.x == 0 && blockIdx.y == 0 && threadIdx.x < 8)
        compute_mats(threadIdx.x, proj, mats);

    int slab = blockIdx.y;
    const float* ip;
    float* op;
    if (slab < 8) { ip = src + (size_t)slab * 32 * HW; op = srcT + (size_t)slab * 32 * HW; }
    else          { ip = ref + (size_t)(slab - 8) * 32 * HW; op = refT + (size_t)(slab - 8) * 32 * HW; }

    int tt = threadIdx.x;
    int q  = tt & 7;             // channel quad: channels 4q..4q+3
    int hl = tt >> 3;            // 0..31 hw lane within tile
    int c0 = 4 * q;
    int hwb = blockIdx.x * 128 + hl;
#pragma unroll
    for (int t4 = 0; t4 < 4; t4++) {
        int hw = hwb + t4 * 32;
        float va = ip[(size_t)(c0 + 0) * HW + hw];
        float vb = ip[(size_t)(c0 + 1) * HW + hw];
        float vc = ip[(size_t)(c0 + 2) * HW + hw];
        float vd = ip[(size_t)(c0 + 3) * HW + hw];
        *(float4*)(op + (size_t)hw * 32 + c0) = make_float4(va, vb, vc, vd);
    }
}

// ---------------------------------------------------------------------------
// Blend 4 taps with bilinear weights and dot with the ref fragment.
// Bitwise-identical expression order to the previous kernel version.
// ---------------------------------------------------------------------------
__device__ __forceinline__ float blend_dot(float4 wv, float4 A, float4 Bv,
                                           float4 Cv, float4 Ev,
                                           v2f Rlo, v2f Rhi) {
    v2f alo = { A.x,  A.y  }, ahi = { A.z,  A.w  };
    v2f blo = { Bv.x, Bv.y }, bhi = { Bv.z, Bv.w };
    v2f clo = { Cv.x, Cv.y }, chi = { Cv.z, Cv.w };
    v2f elo = { Ev.x, Ev.y }, ehi = { Ev.z, Ev.w };
    v2f wlo = wv.x * alo + wv.y * blo + wv.z * clo + wv.w * elo;
    v2f whi = wv.x * ahi + wv.y * bhi + wv.z * chi + wv.w * ehi;
    v2f pr  = wlo * Rlo + whi * Rhi;
    return pr.x + pr.y;
}

// ---------------------------------------------------------------------------
// Kernel 2: main fused kernel. Block = 256 threads = one ref pixel.
// Thread (d,g): d = tid>>3 (depth 0..31), g = tid&7 (channel group).
// XCD swizzle: p = (bid&7)*640 + (bid>>3).
// Phase 1 staging: issue n0..n2 (12 gathers) -> blend n0 -> issue n3 ->
// blend n1,n2 -> interleaved octet-reductions of 0,1,2 (hides n3's L2
// latency) -> blend n3 -> reduce n3. One exposed L2 stall per thread
// instead of two; byte-offset sI (+g*16) gives 1-VALU addressing per tap.
// ---------------------------------------------------------------------------
__global__ __launch_bounds__(256) void main_kernel(
    const float* __restrict__ srcT,   // (N*B, HW, 32) channels-last
    const float* __restrict__ refT,   // (B,   HW, 32) channels-last
    const float* __restrict__ depth,  // (B, D, H, W) original layout
    const float* __restrict__ mats,   // (B*N, 12) rot row-major + trans
    const float* __restrict__ regw,   // (8,)
    const float* __restrict__ regb,   // (1,)
    float* __restrict__ out)          // [B*HW depth][B*D*HW attn]
{
    int tid = threadIdx.x;
    int g  = tid & 7;
    int d  = tid >> 3;      // 0..31

    int bid = blockIdx.x;
    int p   = (bid & 7) * ((BB * HW) / 8) + (bid >> 3);  // XCD-contiguous band
    int b   = p / HW;
    int rem = p - b * HW;
    int y   = rem / WW;
    int x   = rem - y * WW;

    // this thread's group of the ref feature (one float4)
    float4 R = *(const float4*)(refT + (size_t)p * 32 + g * 4);
    v2f Rlo = { R.x, R.y }, Rhi = { R.z, R.w };
    float rwg = regw[g];
    float rb  = regb[0];

    __shared__ float4 sW[NN][DD + 1];          // bilinear weights per (n,d)
    __shared__ int4   sI[NN][DD + 1];          // byte-offset tap indices (*128)
    __shared__ __align__(16) float sLp[DD][8]; // per-depth logits [d][n] (b128 store)
    __shared__ float4 sCWT[DD];                // per-depth cw[4 sources] * 0.25
    __shared__ float  sCWS[DD];                // sum over sources of cw + 1e-8
    __shared__ float  sE[DD];                  // final logits over depth
    __shared__ float  sDep[DD];                // depth hypothesis per d

    // ---- Phase 0 (waves 0-1 only): one thread per (n0, dd) homography
    if (tid < 128) {
        int n0 = tid & 3;
        int dd = tid >> 2;            // 0..31
        float fx = (float)x, fy = (float)y;
        float depM = depth[((size_t)(b * DD + dd) * HH + y) * WW + x];
        const float* Mp = mats + (size_t)(b * NN + n0) * 12;
        float4 m0 = *(const float4*)(Mp);       // rows are 48B -> 16B aligned
        float4 m1 = *(const float4*)(Mp + 4);
        float4 m2 = *(const float4*)(Mp + 8);
        float ax = m0.x * fx + m0.y * fy + m0.z;
        float ay = m0.w * fx + m1.x * fy + m1.y;
        float az = m1.z * fx + m1.w * fy + m2.x;
        float px = ax * depM + m2.y;
        float py = ay * depM + m2.z;
        float pz = az * depM + m2.w;
        float z  = (pz == 0.f) ? 1e-9f : pz;
        float rz = __builtin_amdgcn_rcpf(z);
        float gx = px * rz, gy = py * rz;

        float x0f = floorf(gx), y0f = floorf(gy);
        float wx = gx - x0f, wy = gy - y0f;
        bool vx0 = (x0f >= 0.f)  && (x0f <= (float)(WW - 1));
        bool vx1 = (x0f >= -1.f) && (x0f <= (float)(WW - 2));
        bool vy0 = (y0f >= 0.f)  && (y0f <= (float)(HH - 1));
        bool vy1 = (y0f >= -1.f) && (y0f <= (float)(HH - 2));
        float W00 = (vx0 && vy0) ? (1.f - wx) * (1.f - wy) : 0.f;
        float W10 = (vx1 && vy0) ? wx * (1.f - wy)         : 0.f;
        float W01 = (vx0 && vy1) ? (1.f - wx) * wy         : 0.f;
        float W11 = (vx1 && vy1) ? wx * wy                 : 0.f;

        int xi0 = (int)fminf(fmaxf(x0f,       0.f), (float)(WW - 1));
        int xi1 = (int)fminf(fmaxf(x0f + 1.f, 0.f), (float)(WW - 1));
        int yi0 = (int)fminf(fmaxf(y0f,       0.f), (float)(HH - 1));
        int yi1 = (int)fminf(fmaxf(y0f + 1.f, 0.f), (float)(HH - 1));

        sW[n0][dd] = make_float4(W00, W10, W01, W11);
        // byte offsets: pixel * 32ch * 4B = *128
        sI[n0][dd] = make_int4((yi0 * WW + xi0) * 128, (yi0 * WW + xi1) * 128,
                               (yi1 * WW + xi0) * 128, (yi1 * WW + xi1) * 128);
        if (n0 == 0) sDep[dd] = depM;
    }
    __syncthreads();   // barrier 0: sW/sI/sDep populated

    // ---- Phase 1: staged gathers + packed blend/dot + interleaved g-sums
    float4 wv0 = sW[0][d], wv1 = sW[1][d], wv2 = sW[2][d], wv3 = sW[3][d];
    int4   iv0 = sI[0][d], iv1 = sI[1][d], iv2 = sI[2][d], iv3 = sI[3][d];
    unsigned g16 = (unsigned)(g * 16);

    const char* S0 = (const char*)srcT + (size_t)(0 * BB + b) * (32 * HW) * 4;
    const char* S1 = (const char*)srcT + (size_t)(1 * BB + b) * (32 * HW) * 4;
    const char* S2 = (const char*)srcT + (size_t)(2 * BB + b) * (32 * HW) * 4;
    const char* S3 = (const char*)srcT + (size_t)(3 * BB + b) * (32 * HW) * 4;

    // issue sources 0..2 (12 gathers)
    float4 a0 = *(const float4*)(S0 + ((unsigned)iv0.x + g16));
    float4 b0 = *(const float4*)(S0 + ((unsigned)iv0.y + g16));
    float4 c0 = *(const float4*)(S0 + ((unsigned)iv0.z + g16));
    float4 e0 = *(const float4*)(S0 + ((unsigned)iv0.w + g16));
    float4 a1 = *(const float4*)(S1 + ((unsigned)iv1.x + g16));
    float4 b1 = *(const float4*)(S1 + ((unsigned)iv1.y + g16));
    float4 c1 = *(const float4*)(S1 + ((unsigned)iv1.z + g16));
    float4 e1 = *(const float4*)(S1 + ((unsigned)iv1.w + g16));
    float4 a2 = *(const float4*)(S2 + ((unsigned)iv2.x + g16));
    float4 b2 = *(const float4*)(S2 + ((unsigned)iv2.y + g16));
    float4 c2 = *(const float4*)(S2 + ((unsigned)iv2.z + g16));
    float4 e2 = *(const float4*)(S2 + ((unsigned)iv2.w + g16));

    // blend source 0 (frees its 4 regs), then issue source 3
    float cor0 = blend_dot(wv0, a0, b0, c0, e0, Rlo, Rhi);

    float4 a3 = *(const float4*)(S3 + ((unsigned)iv3.x + g16));
    float4 b3 = *(const float4*)(S3 + ((unsigned)iv3.y + g16));
    float4 c3 = *(const float4*)(S3 + ((unsigned)iv3.z + g16));
    float4 e3 = *(const float4*)(S3 + ((unsigned)iv3.w + g16));

    float cor1 = blend_dot(wv1, a1, b1, c1, e1, Rlo, Rhi);
    float cor2 = blend_dot(wv2, a2, b2, c2, e2, Rlo, Rhi);

    // interleaved octet reductions for 0,1,2 — hides source 3's L2 latency
    float r0 = cor0, r1 = cor1, r2 = cor2;
    r0 += __shfl_xor(r0, 1); r1 += __shfl_xor(r1, 1); r2 += __shfl_xor(r2, 1);
    r0 += __shfl_xor(r0, 2); r1 += __shfl_xor(r1, 2); r2 += __shfl_xor(r2, 2);
    r0 += __shfl_xor(r0, 4); r1 += __shfl_xor(r1, 4); r2 += __shfl_xor(r2, 4);

    float cor3 = blend_dot(wv3, a3, b3, c3, e3, Rlo, Rhi);
    float r3 = cor3;
    r3 += __shfl_xor(r3, 1);
    r3 += __shfl_xor(r3, 2);
    r3 += __shfl_xor(r3, 4);

    if (g == 0)
        *(float4*)&sLp[d][0] = make_float4(r0 * 0.125f, r1 * 0.125f,
                                           r2 * 0.125f, r3 * 0.125f);
    __syncthreads();   // barrier 1: sLp fully populated

    // ---- Stats: wave 0 computes cw tables for all n,d
    if (tid < 64) {
        int n  = tid >> 4;       // 0..3
        int dh = tid & 15;       // 0..15; covers d=dh and d=dh+16
        float l0 = sLp[dh][n];
        float l1 = sLp[dh + 16][n];
        float m = fmaxf(l0, l1);
        m = fmaxf(m, __shfl_xor(m, 1));
        m = fmaxf(m, __shfl_xor(m, 2));
        m = fmaxf(m, __shfl_xor(m, 4));
        m = fmaxf(m, __shfl_xor(m, 8));
        float e0s = __expf(l0 - m), e1s = __expf(l1 - m);
        float s = e0s + e1s;
        s += __shfl_xor(s, 1);
        s += __shfl_xor(s, 2);
        s += __shfl_xor(s, 4);
        s += __shfl_xor(s, 8);
        float f = 0.17677669529663687f / s;   // fold 1/sqrt(C=32)
        float c0s = e0s * f, c1s = e1s * f;
        // transposed, 0.25 (mean over C//G=4) pre-folded for phase 2's b128 read
        ((float*)&sCWT[dh])[n]      = c0s * 0.25f;
        ((float*)&sCWT[dh + 16])[n] = c1s * 0.25f;
        // cross-source sum per depth (lanes with same dh across the 4 n-groups)
        float t0 = c0s, t1 = c1s;
        t0 += __shfl_xor(t0, 16); t0 += __shfl_xor(t0, 32);
        t1 += __shfl_xor(t1, 16); t1 += __shfl_xor(t1, 32);
        if (n == 0) {
            sCWS[dh]      = t0 + 1e-8f;
            sCWS[dh + 16] = t1 + 1e-8f;
        }
    }
    __syncthreads();   // barrier 2: sCWT/sCWS ready

    // ---- Phase 2: per-thread weighted accumulation + reg projection
    float4 cwv = sCWT[d];
    float cf = cwv.x * cor0 + cwv.y * cor1 + cwv.z * cor2 + cwv.w * cor3;
    float v = cf * rwg;
    v += __shfl_xor(v, 1);
    v += __shfl_xor(v, 2);
    v += __shfl_xor(v, 4);
    float logit2 = v * __builtin_amdgcn_rcpf(sCWS[d]) + rb;  // same across octet
    if (g == 0) sE[d] = logit2;
    __syncthreads();   // barrier 3: sE fully populated

    // ---- Final: wave 0 alone — softmax over D, attn writes, argmax depth
    if (tid < 64) {
        int dl = tid & 31;               // both wave halves compute identically
        float q = sE[dl];
        float m2 = q;
        m2 = fmaxf(m2, __shfl_xor(m2, 1));
        m2 = fmaxf(m2, __shfl_xor(m2, 2));
        m2 = fmaxf(m2, __shfl_xor(m2, 4));
        m2 = fmaxf(m2, __shfl_xor(m2, 8));
        m2 = fmaxf(m2, __shfl_xor(m2, 16));
        float e2 = __expf(q - m2);
        float t2 = e2;
        t2 += __shfl_xor(t2, 1);
        t2 += __shfl_xor(t2, 2);
        t2 += __shfl_xor(t2, 4);
        t2 += __shfl_xor(t2, 8);
        t2 += __shfl_xor(t2, 16);
        float aw = e2 / t2;
        if (tid < 32)
            out[(size_t)BB * HW + (size_t)(b * DD + dl) * HW + rem] = aw;

        // argmax over D (first-max semantics), within each 32-lane half
        float bv = q; int bi = dl;
#pragma unroll
        for (int s = 1; s <= 16; s <<= 1) {
            float ov = __shfl_xor(bv, s);
            int   oi = __shfl_xor(bi, s);
            if (ov > bv || (ov == bv && oi < bi)) { bv = ov; bi = oi; }
        }
        if (tid < 32 && dl == bi) out[p] = sDep[bi];
    }
}

// ---------------------------------------------------------------------------
extern "C" void kernel_launch(void* const* d_in, const int* in_sizes, int n_in,
                              void* d_out, int out_size, void* d_ws, size_t ws_size,
                              hipStream_t stream) {
    const float* ref   = (const float*)d_in[0];  // (B,C,H,W)
    const float* src   = (const float*)d_in[1];  // (N,B,C,H,W)
    const float* proj  = (const float*)d_in[2];  // (B,N+1,2,4,4)
    const float* depth = (const float*)d_in[3];  // (B,D,H,W)
    const float* regw  = (const float*)d_in[4];  // (8,)
    const float* regb  = (const float*)d_in[5];  // (1,)
    float* out = (float*)d_out;

    float* ws   = (float*)d_ws;
    float* mats = ws;                                 // 96 floats (pad to 256)
    float* srcT = ws + 256;                           // N*B*HW*32 = 5,242,880
    float* refT = srcT + (size_t)NN * BB * HW * 32;   // B*HW*32 = 1,310,720

    prep_transpose<<<dim3(HW / 128, 10), 256, 0, stream>>>(src, ref, proj,
                                                           srcT, refT, mats);
    main_kernel<<<BB * HW, 256, 0, stream>>>(srcT, refT, depth, mats,
                                             regw, regb, out);
}

// Round 4
// 188.905 us; speedup vs baseline: 1.0104x; 1.0104x over previous
//
#include <hip/hip_runtime.h>
#include <math.h>

// Problem constants (from reference setup_inputs)
#define BB 2
#define CC 32
#define HH 128
#define WW 160
#define DD 32
#define NN 4
#define HW (HH * WW)        // 20480
#define GG 8

typedef float v2f __attribute__((ext_vector_type(2)));

// ---------------------------------------------------------------------------
// Device helper: per-(b,src) projection matrices (FP64 Gauss-Jordan).
// Executed by threads 0..7 of block (0,0) of the prep kernel (round-0 best).
// ---------------------------------------------------------------------------
__device__ void compute_mats(int t, const float* __restrict__ proj,
                             float* __restrict__ mats) {
    int b = t >> 2, n = t & 3;
    const float* Er = proj + ((size_t)(b * (NN + 1) + 0) * 2 + 0) * 16;
    const float* Kr = proj + ((size_t)(b * (NN + 1) + 0) * 2 + 1) * 16;
    const float* Es = proj + ((size_t)(b * (NN + 1) + n + 1) * 2 + 0) * 16;
    const float* Ks = proj + ((size_t)(b * (NN + 1) + n + 1) * 2 + 1) * 16;

    double A[4][4], Bm[4][4];
    for (int r = 0; r < 4; r++)
        for (int c = 0; c < 4; c++) {
            if (r < 3) {
                A[r][c]  = (double)Kr[r*4+0]*Er[0*4+c] + (double)Kr[r*4+1]*Er[1*4+c] + (double)Kr[r*4+2]*Er[2*4+c];
                Bm[r][c] = (double)Ks[r*4+0]*Es[0*4+c] + (double)Ks[r*4+1]*Es[1*4+c] + (double)Ks[r*4+2]*Es[2*4+c];
            } else {
                A[r][c]  = (double)Er[12 + c];
                Bm[r][c] = (double)Es[12 + c];
            }
        }
    double M[4][8];
    for (int i = 0; i < 4; i++)
        for (int j = 0; j < 4; j++) { M[i][j] = A[i][j]; M[i][4+j] = (i == j) ? 1.0 : 0.0; }
    for (int col = 0; col < 4; col++) {
        int piv = col;
        for (int r = col + 1; r < 4; r++)
            if (fabs(M[r][col]) > fabs(M[piv][col])) piv = r;
        if (piv != col)
            for (int j = 0; j < 8; j++) { double tmp = M[col][j]; M[col][j] = M[piv][j]; M[piv][j] = tmp; }
        double pv = M[col][col];
        for (int j = 0; j < 8; j++) M[col][j] /= pv;
        for (int r = 0; r < 4; r++) {
            if (r == col) continue;
            double f = M[r][col];
            for (int j = 0; j < 8; j++) M[r][j] -= f * M[col][j];
        }
    }
    float* o = mats + t * 12;
    for (int i = 0; i < 3; i++) {
        double p0 = 0, p1 = 0, p2 = 0, p3 = 0;
        for (int k = 0; k < 4; k++) {
            p0 += Bm[i][k] * M[k][4+0];
            p1 += Bm[i][k] * M[k][4+1];
            p2 += Bm[i][k] * M[k][4+2];
            p3 += Bm[i][k] * M[k][4+3];
        }
        o[i*3+0] = (float)p0; o[i*3+1] = (float)p1; o[i*3+2] = (float)p2;
        o[9 + i] = (float)p3;
    }
}

// ---------------------------------------------------------------------------
// Kernel 1 (round-0 exact): merged LDS transpose [32][HW] -> [HW][32].
// slabs 0-7 = src, 8-9 = ref. One float4 read + one float4 write per thread.
// Block (0,0) additionally computes the 8 projection matrices (tid<8).
// ---------------------------------------------------------------------------
__global__ __launch_bounds__(256) void prep_transpose(const float* __restrict__ src,
                                                      const float* __restrict__ ref,
                                                      const float* __restrict__ proj,
                                                      float* __restrict__ srcT,
                                                      float* __restrict__ refT,
                                                      float* __restrict__ mats) {
    if (blockIdx.x == 0 && blockIdx.y == 0 && threadIdx.x < 8)
        compute_mats(threadIdx.x, proj, mats);

    __shared__ float t[32][33];
    int slab = blockIdx.y;
    const float* ip;
    float* op;
    if (slab < 8) { ip = src + (size_t)slab * 32 * HW; op = srcT + (size_t)slab * 32 * HW; }
    else          { ip = ref + (size_t)(slab - 8) * 32 * HW; op = refT + (size_t)(slab - 8) * 32 * HW; }
    int hw0 = blockIdx.x * 32;
    int tt = threadIdx.x;
    int c  = tt >> 3;            // 0..31 (channel)
    int q  = tt & 7;             // 0..7  (quad within 32)

    float4 rv = *(const float4*)(ip + (size_t)c * HW + hw0 + 4 * q);
    t[c][4 * q + 0] = rv.x;
    t[c][4 * q + 1] = rv.y;
    t[c][4 * q + 2] = rv.z;
    t[c][4 * q + 3] = rv.w;
    __syncthreads();

    int hl = tt >> 3;            // 0..31 (hw within tile)
    float4 wv;
    wv.x = t[4 * q + 0][hl];
    wv.y = t[4 * q + 1][hl];
    wv.z = t[4 * q + 2][hl];
    wv.w = t[4 * q + 3][hl];
    *(float4*)(op + (size_t)(hw0 + hl) * 32 + 4 * q) = wv;
}

// ---------------------------------------------------------------------------
// Helpers for the paired-pixel main kernel. All arithmetic expression orders
// are bit-identical to the round-0 kernel.
// ---------------------------------------------------------------------------
__device__ __forceinline__ void homog_setup(int t, int bb, int y, int x,
        const float* __restrict__ depth, const float* __restrict__ mats,
        float4 (*sWs)[DD + 1], int4 (*sIs)[DD + 1], float* sDeps) {
    int n0 = t & 3;
    int dd = t >> 2;              // 0..31
    float fx = (float)x, fy = (float)y;
    float depM = depth[((size_t)(bb * DD + dd) * HH + y) * WW + x];
    const float* Mp = mats + (size_t)(bb * NN + n0) * 12;
    float4 m0 = *(const float4*)(Mp);       // rows are 48B -> 16B aligned
    float4 m1 = *(const float4*)(Mp + 4);
    float4 m2 = *(const float4*)(Mp + 8);
    float ax = m0.x * fx + m0.y * fy + m0.z;
    float ay = m0.w * fx + m1.x * fy + m1.y;
    float az = m1.z * fx + m1.w * fy + m2.x;
    float px = ax * depM + m2.y;
    float py = ay * depM + m2.z;
    float pz = az * depM + m2.w;
    float z  = (pz == 0.f) ? 1e-9f : pz;
    float rz = __builtin_amdgcn_rcpf(z);
    float gx = px * rz, gy = py * rz;

    float x0f = floorf(gx), y0f = floorf(gy);
    float wx = gx - x0f, wy = gy - y0f;
    bool vx0 = (x0f >= 0.f)  && (x0f <= (float)(WW - 1));
    bool vx1 = (x0f >= -1.f) && (x0f <= (float)(WW - 2));
    bool vy0 = (y0f >= 0.f)  && (y0f <= (float)(HH - 1));
    bool vy1 = (y0f >= -1.f) && (y0f <= (float)(HH - 2));
    float W00 = (vx0 && vy0) ? (1.f - wx) * (1.f - wy) : 0.f;
    float W10 = (vx1 && vy0) ? wx * (1.f - wy)         : 0.f;
    float W01 = (vx0 && vy1) ? (1.f - wx) * wy         : 0.f;
    float W11 = (vx1 && vy1) ? wx * wy                 : 0.f;

    int xi0 = (int)fminf(fmaxf(x0f,       0.f), (float)(WW - 1));
    int xi1 = (int)fminf(fmaxf(x0f + 1.f, 0.f), (float)(WW - 1));
    int yi0 = (int)fminf(fmaxf(y0f,       0.f), (float)(HH - 1));
    int yi1 = (int)fminf(fmaxf(y0f + 1.f, 0.f), (float)(HH - 1));

    sWs[n0][dd] = make_float4(W00, W10, W01, W11);
    sIs[n0][dd] = make_int4((yi0 * WW + xi0) * 8, (yi0 * WW + xi1) * 8,
                            (yi1 * WW + xi0) * 8, (yi1 * WW + xi1) * 8);
    if (n0 == 0) sDeps[dd] = depM;
}

// blend 4 taps + dot with ref fragment + octet reduce + optional sL store
__device__ __forceinline__ float consume_src(float4 wv, float4 A, float4 Bv,
                                             float4 Cv, float4 Ev,
                                             v2f Rlo, v2f Rhi, int g, int d,
                                             float* sLrow) {
    v2f alo = { A.x,  A.y  }, ahi = { A.z,  A.w  };
    v2f blo = { Bv.x, Bv.y }, bhi = { Bv.z, Bv.w };
    v2f clo = { Cv.x, Cv.y }, chi = { Cv.z, Cv.w };
    v2f elo = { Ev.x, Ev.y }, ehi = { Ev.z, Ev.w };
    v2f wlo = wv.x * alo + wv.y * blo + wv.z * clo + wv.w * elo;
    v2f whi = wv.x * ahi + wv.y * bhi + wv.z * chi + wv.w * ehi;
    v2f pr  = wlo * Rlo + whi * Rhi;
    float cr = pr.x + pr.y;
    float ls = cr;
    ls += __shfl_xor(ls, 1);
    ls += __shfl_xor(ls, 2);
    ls += __shfl_xor(ls, 4);
    if (g == 0) sLrow[d] = ls * 0.125f;
    return cr;
}

// per-source softmax over depth -> cw tables (one 64-lane wave; lane = tid&63)
__device__ __forceinline__ void stats_fn(int lane, const float (*sLs)[DD + 8],
                                         float4* sCWTs, float* sCWSs) {
    int n  = lane >> 4;       // 0..3
    int dh = lane & 15;       // 0..15; covers d=dh and d=dh+16
    float l0 = sLs[n][dh];
    float l1 = sLs[n][dh + 16];
    float m = fmaxf(l0, l1);
    m = fmaxf(m, __shfl_xor(m, 1));
    m = fmaxf(m, __shfl_xor(m, 2));
    m = fmaxf(m, __shfl_xor(m, 4));
    m = fmaxf(m, __shfl_xor(m, 8));
    float e0s = __expf(l0 - m), e1s = __expf(l1 - m);
    float s = e0s + e1s;
    s += __shfl_xor(s, 1);
    s += __shfl_xor(s, 2);
    s += __shfl_xor(s, 4);
    s += __shfl_xor(s, 8);
    float f = 0.17677669529663687f / s;   // fold 1/sqrt(C=32)
    float c0s = e0s * f, c1s = e1s * f;
    ((float*)&sCWTs[dh])[n]      = c0s * 0.25f;
    ((float*)&sCWTs[dh + 16])[n] = c1s * 0.25f;
    float t0 = c0s, t1 = c1s;
    t0 += __shfl_xor(t0, 16); t0 += __shfl_xor(t0, 32);
    t1 += __shfl_xor(t1, 16); t1 += __shfl_xor(t1, 32);
    if (n == 0) {
        sCWSs[dh]      = t0 + 1e-8f;
        sCWSs[dh + 16] = t1 + 1e-8f;
    }
}

// softmax over D + attn writes + argmax depth (wave 0; lane = tid)
__device__ __forceinline__ void final_fn(int lane, const float* sEs,
                                         const float* sDeps, float* out,
                                         int b, int rem, int p) {
    int dl = lane & 31;               // both wave halves compute identically
    float q = sEs[dl];
    float m2 = q;
    m2 = fmaxf(m2, __shfl_xor(m2, 1));
    m2 = fmaxf(m2, __shfl_xor(m2, 2));
    m2 = fmaxf(m2, __shfl_xor(m2, 4));
    m2 = fmaxf(m2, __shfl_xor(m2, 8));
    m2 = fmaxf(m2, __shfl_xor(m2, 16));
    float e2 = __expf(q - m2);
    float t2 = e2;
    t2 += __shfl_xor(t2, 1);
    t2 += __shfl_xor(t2, 2);
    t2 += __shfl_xor(t2, 4);
    t2 += __shfl_xor(t2, 8);
    t2 += __shfl_xor(t2, 16);
    float aw = e2 / t2;
    if (lane < 32)
        out[(size_t)BB * HW + (size_t)(b * DD + dl) * HW + rem] = aw;

    float bv = q; int bi = dl;
#pragma unroll
    for (int s = 1; s <= 16; s <<= 1) {
        float ov = __shfl_xor(bv, s);
        int   oi = __shfl_xor(bi, s);
        if (ov > bv || (ov == bv && oi < bi)) { bv = ov; bi = oi; }
    }
    if (lane < 32 && dl == bi) out[p] = sDeps[bi];
}

// ---------------------------------------------------------------------------
// Kernel 2: paired-pixel fused kernel. Block = 256 threads = TWO adjacent
// ref pixels (p0 = 2w, p1 = 2w+1; same XCD band). Interleaved schedule:
//   bar0: homographies for A (tid<128) and B (tid>=128)
//   bar1: phase1(A) gathers -> corA, sL[0]
//   bar2: phase1(B) gathers  ||  wave0: stats(A)      <- overlap
//   bar3: phase2(A) -> sE[0] ||  wave1: stats(B)      <- overlap
//   bar4: phase2(B) -> sE[1] ||  wave0: final(A)      <- overlap
//   end : wave0: final(B)
// B's taps share ~90% of A's cachelines -> L1/L2-hot refetch.
// ---------------------------------------------------------------------------
__global__ __launch_bounds__(256) void main_kernel(
    const float* __restrict__ srcT,   // (N*B, HW, 32) channels-last
    const float* __restrict__ refT,   // (B,   HW, 32) channels-last
    const float* __restrict__ depth,  // (B, D, H, W) original layout
    const float* __restrict__ mats,   // (B*N, 12) rot row-major + trans
    const float* __restrict__ regw,   // (8,)
    const float* __restrict__ regb,   // (1,)
    float* __restrict__ out)          // [B*HW depth][B*D*HW attn]
{
    int tid = threadIdx.x;
    int g  = tid & 7;
    int d  = tid >> 3;      // 0..31

    int q   = blockIdx.x;                                 // 0..20479
    int w   = (q & 7) * ((BB * HW / 2) / 8) + (q >> 3);   // XCD-contiguous band
    int p0  = 2 * w;
    int p1  = p0 + 1;                                     // same b (HW even)
    int b   = p0 / HW;
    int rem0 = p0 - b * HW;
    int rem1 = rem0 + 1;
    int y0p = rem0 / WW, x0p = rem0 - y0p * WW;
    int y1p = rem1 / WW, x1p = rem1 - y1p * WW;

    // ref fragments for both pixels (adjacent 128B records)
    float4 RA = *(const float4*)(refT + (size_t)p0 * 32 + g * 4);
    float4 RB = *(const float4*)(refT + (size_t)p1 * 32 + g * 4);
    v2f RAlo = { RA.x, RA.y }, RAhi = { RA.z, RA.w };
    v2f RBlo = { RB.x, RB.y }, RBhi = { RB.z, RB.w };
    float rwg = regw[g];
    float rb  = regb[0];

    __shared__ float4 sW[2][NN][DD + 1];
    __shared__ int4   sI[2][NN][DD + 1];
    __shared__ float  sL[2][NN][DD + 8];
    __shared__ float4 sCWT[2][DD];
    __shared__ float  sCWS[2][DD];
    __shared__ float  sE[2][DD];
    __shared__ float  sDep[2][DD];

    // ---- Phase 0: homographies for both pixels (128 threads each)
    if (tid < 128) homog_setup(tid,       b, y0p, x0p, depth, mats, sW[0], sI[0], sDep[0]);
    else           homog_setup(tid - 128, b, y1p, x1p, depth, mats, sW[1], sI[1], sDep[1]);
    __syncthreads();   // barrier 0

    const float4* S0 = (const float4*)(srcT + (size_t)(0 * BB + b) * (32 * HW)) + g;
    const float4* S1 = (const float4*)(srcT + (size_t)(1 * BB + b) * (32 * HW)) + g;
    const float4* S2 = (const float4*)(srcT + (size_t)(2 * BB + b) * (32 * HW)) + g;
    const float4* S3 = (const float4*)(srcT + (size_t)(3 * BB + b) * (32 * HW)) + g;

    float corA[NN], corB[NN];

    // ---- Phase 1A: pairwise-batched gathers for pixel A (round-0 exact)
    {
        float4 wv0 = sW[0][0][d]; int4 iv0 = sI[0][0][d];
        float4 wv1 = sW[0][1][d]; int4 iv1 = sI[0][1][d];
        float4 a0 = S0[iv0.x], b0 = S0[iv0.y], c0 = S0[iv0.z], e0 = S0[iv0.w];
        float4 a1 = S1[iv1.x], b1 = S1[iv1.y], c1 = S1[iv1.z], e1 = S1[iv1.w];
        corA[0] = consume_src(wv0, a0, b0, c0, e0, RAlo, RAhi, g, d, &sL[0][0][0]);
        corA[1] = consume_src(wv1, a1, b1, c1, e1, RAlo, RAhi, g, d, &sL[0][1][0]);

        float4 wv2 = sW[0][2][d]; int4 iv2 = sI[0][2][d];
        float4 wv3 = sW[0][3][d]; int4 iv3 = sI[0][3][d];
        float4 a2 = S2[iv2.x], b2 = S2[iv2.y], c2 = S2[iv2.z], e2 = S2[iv2.w];
        float4 a3 = S3[iv3.x], b3 = S3[iv3.y], c3 = S3[iv3.z], e3 = S3[iv3.w];
        corA[2] = consume_src(wv2, a2, b2, c2, e2, RAlo, RAhi, g, d, &sL[0][2][0]);
        corA[3] = consume_src(wv3, a3, b3, c3, e3, RAlo, RAhi, g, d, &sL[0][3][0]);
    }
    __syncthreads();   // barrier 1: sL[0] populated

    // ---- Phase 1B gathers  ||  wave 0 runs stats(A) under B's load latency
    {
        float4 wv0 = sW[1][0][d]; int4 iv0 = sI[1][0][d];
        float4 wv1 = sW[1][1][d]; int4 iv1 = sI[1][1][d];
        float4 a0 = S0[iv0.x], b0 = S0[iv0.y], c0 = S0[iv0.z], e0 = S0[iv0.w];
        float4 a1 = S1[iv1.x], b1 = S1[iv1.y], c1 = S1[iv1.z], e1 = S1[iv1.w];

        if (tid < 64) stats_fn(tid, sL[0], sCWT[0], sCWS[0]);   // overlap

        corB[0] = consume_src(wv0, a0, b0, c0, e0, RBlo, RBhi, g, d, &sL[1][0][0]);
        corB[1] = consume_src(wv1, a1, b1, c1, e1, RBlo, RBhi, g, d, &sL[1][1][0]);

        float4 wv2 = sW[1][2][d]; int4 iv2 = sI[1][2][d];
        float4 wv3 = sW[1][3][d]; int4 iv3 = sI[1][3][d];
        float4 a2 = S2[iv2.x], b2 = S2[iv2.y], c2 = S2[iv2.z], e2 = S2[iv2.w];
        float4 a3 = S3[iv3.x], b3 = S3[iv3.y], c3 = S3[iv3.z], e3 = S3[iv3.w];
        corB[2] = consume_src(wv2, a2, b2, c2, e2, RBlo, RBhi, g, d, &sL[1][2][0]);
        corB[3] = consume_src(wv3, a3, b3, c3, e3, RBlo, RBhi, g, d, &sL[1][3][0]);
    }
    __syncthreads();   // barrier 2: sCWT[0]/sCWS[0] + sL[1] ready

    // ---- Phase 2A (all threads)  ||  wave 1 runs stats(B)
    {
        float4 cwv = sCWT[0][d];
        float cf = cwv.x * corA[0] + cwv.y * corA[1] + cwv.z * corA[2] + cwv.w * corA[3];
        float vv = cf * rwg;
        vv += __shfl_xor(vv, 1);
        vv += __shfl_xor(vv, 2);
        vv += __shfl_xor(vv, 4);
        float logit2 = vv * __builtin_amdgcn_rcpf(sCWS[0][d]) + rb;
        if (g == 0) sE[0][d] = logit2;
    }
    if (tid >= 64 && tid < 128) stats_fn(tid - 64, sL[1], sCWT[1], sCWS[1]);
    __syncthreads();   // barrier 3: sE[0] + sCWT[1]/sCWS[1] ready

    // ---- Phase 2B (all threads)  ||  wave 0 runs final(A)
    {
        float4 cwv = sCWT[1][d];
        float cf = cwv.x * corB[0] + cwv.y * corB[1] + cwv.z * corB[2] + cwv.w * corB[3];
        float vv = cf * rwg;
        vv += __shfl_xor(vv, 1);
        vv += __shfl_xor(vv, 2);
        vv += __shfl_xor(vv, 4);
        float logit2 = vv * __builtin_amdgcn_rcpf(sCWS[1][d]) + rb;
        if (g == 0) sE[1][d] = logit2;
    }
    if (tid < 64) final_fn(tid, sE[0], sDep[0], out, b, rem0, p0);
    __syncthreads();   // barrier 4: sE[1] ready

    if (tid < 64) final_fn(tid, sE[1], sDep[1], out, b, rem1, p1);
}

// ---------------------------------------------------------------------------
extern "C" void kernel_launch(void* const* d_in, const int* in_sizes, int n_in,
                              void* d_out, int out_size, void* d_ws, size_t ws_size,
                              hipStream_t stream) {
    const float* ref   = (const float*)d_in[0];  // (B,C,H,W)
    const float* src   = (const float*)d_in[1];  // (N,B,C,H,W)
    const float* proj  = (const float*)d_in[2];  // (B,N+1,2,4,4)
    const float* depth = (const float*)d_in[3];  // (B,D,H,W)
    const float* regw  = (const float*)d_in[4];  // (8,)
    const float* regb  = (const float*)d_in[5];  // (1,)
    float* out = (float*)d_out;

    float* ws   = (float*)d_ws;
    float* mats = ws;                                 // 96 floats (pad to 256)
    float* srcT = ws + 256;                           // N*B*HW*32 = 5,242,880
    float* refT = srcT + (size_t)NN * BB * HW * 32;   // B*HW*32 = 1,310,720

    prep_transpose<<<dim3(HW / 32, 10), 256, 0, stream>>>(src, ref, proj,
                                                          srcT, refT, mats);
    main_kernel<<<BB * HW / 2, 256, 0, stream>>>(srcT, refT, depth, mats,
                                                 regw, regb, out);
}

// Round 5
// 183.747 us; speedup vs baseline: 1.0388x; 1.0281x over previous
//
#include <hip/hip_runtime.h>
#include <hip/hip_bf16.h>
#include <math.h>

// Problem constants (from reference setup_inputs)
#define BB 2
#define CC 32
#define HH 128
#define WW 160
#define DD 32
#define NN 4
#define HW (HH * WW)        // 20480
#define GG 8

typedef float v2f __attribute__((ext_vector_type(2)));

// ---------------------------------------------------------------------------
// Device helper: per-(b,src) projection matrices (FP64 Gauss-Jordan).
// Executed by threads 0..7 of one block of the prep kernel.
// ---------------------------------------------------------------------------
__device__ void compute_mats(int t, const float* __restrict__ proj,
                             float* __restrict__ mats) {
    int b = t >> 2, n = t & 3;
    const float* Er = proj + ((size_t)(b * (NN + 1) + 0) * 2 + 0) * 16;
    const float* Kr = proj + ((size_t)(b * (NN + 1) + 0) * 2 + 1) * 16;
    const float* Es = proj + ((size_t)(b * (NN + 1) + n + 1) * 2 + 0) * 16;
    const float* Ks = proj + ((size_t)(b * (NN + 1) + n + 1) * 2 + 1) * 16;

    double A[4][4], Bm[4][4];
    for (int r = 0; r < 4; r++)
        for (int c = 0; c < 4; c++) {
            if (r < 3) {
                A[r][c]  = (double)Kr[r*4+0]*Er[0*4+c] + (double)Kr[r*4+1]*Er[1*4+c] + (double)Kr[r*4+2]*Er[2*4+c];
                Bm[r][c] = (double)Ks[r*4+0]*Es[0*4+c] + (double)Ks[r*4+1]*Es[1*4+c] + (double)Ks[r*4+2]*Es[2*4+c];
            } else {
                A[r][c]  = (double)Er[12 + c];
                Bm[r][c] = (double)Es[12 + c];
            }
        }
    double M[4][8];
    for (int i = 0; i < 4; i++)
        for (int j = 0; j < 4; j++) { M[i][j] = A[i][j]; M[i][4+j] = (i == j) ? 1.0 : 0.0; }
    for (int col = 0; col < 4; col++) {
        int piv = col;
        for (int r = col + 1; r < 4; r++)
            if (fabs(M[r][col]) > fabs(M[piv][col])) piv = r;
        if (piv != col)
            for (int j = 0; j < 8; j++) { double tmp = M[col][j]; M[col][j] = M[piv][j]; M[piv][j] = tmp; }
        double pv = M[col][col];
        for (int j = 0; j < 8; j++) M[col][j] /= pv;
        for (int r = 0; r < 4; r++) {
            if (r == col) continue;
            double f = M[r][col];
            for (int j = 0; j < 8; j++) M[r][j] -= f * M[col][j];
        }
    }
    float* o = mats + t * 12;
    for (int i = 0; i < 3; i++) {
        double p0 = 0, p1 = 0, p2 = 0, p3 = 0;
        for (int k = 0; k < 4; k++) {
            p0 += Bm[i][k] * M[k][4+0];
            p1 += Bm[i][k] * M[k][4+1];
            p2 += Bm[i][k] * M[k][4+2];
            p3 += Bm[i][k] * M[k][4+3];
        }
        o[i*3+0] = (float)p0; o[i*3+1] = (float)p1; o[i*3+2] = (float)p2;
        o[9 + i] = (float)p3;
    }
}

// ---------------------------------------------------------------------------
// Kernel 1: merged transpose [32][HW] -> [HW][32]; slabs 0-7 = src, 8-9 = ref.
// Vectorized: ONE float4 global read + ONE float4 global write per thread.
// Block (0,0) additionally computes the 8 projection matrices (tid<8).
// ---------------------------------------------------------------------------
__global__ __launch_bounds__(256) void prep_transpose(const float* __restrict__ src,
                                                      const float* __restrict__ ref,
                                                      const float* __restrict__ proj,
                                                      float* __restrict__ srcT,
                                                      float* __restrict__ refT,
                                                      float* __restrict__ mats) {
    if (blockIdx.x == 0 && blockIdx.y == 0 && threadIdx.x < 8)
        compute_mats(threadIdx.x, proj, mats);

    __shared__ float t[32][33];
    int slab = blockIdx.y;
    const float* ip;
    float* op;
    if (slab < 8) { ip = src + (size_t)slab * 32 * HW; op = srcT + (size_t)slab * 32 * HW; }
    else          { ip = ref + (size_t)(slab - 8) * 32 * HW; op = refT + (size_t)(slab - 8) * 32 * HW; }
    int hw0 = blockIdx.x * 32;
    int tt = threadIdx.x;
    int c  = tt >> 3;            // 0..31 (channel)
    int q  = tt & 7;             // 0..7  (quad within 32)

    float4 rv = *(const float4*)(ip + (size_t)c * HW + hw0 + 4 * q);
    t[c][4 * q + 0] = rv.x;
    t[c][4 * q + 1] = rv.y;
    t[c][4 * q + 2] = rv.z;
    t[c][4 * q + 3] = rv.w;
    __syncthreads();

    int hl = tt >> 3;            // 0..31 (hw within tile)
    float4 wv;
    wv.x = t[4 * q + 0][hl];
    wv.y = t[4 * q + 1][hl];
    wv.z = t[4 * q + 2][hl];
    wv.w = t[4 * q + 3][hl];
    *(float4*)(op + (size_t)(hw0 + hl) * 32 + 4 * q) = wv;
}

// ---------------------------------------------------------------------------
// Kernel 2: main fused kernel. Block = 256 threads = one ref pixel.
// Thread (d,g): d = tid>>3 (depth 0..31), g = tid&7 (channel group).
// XCD swizzle: p = (bid&7)*640 + (bid>>3).
// Phase 1 batches sources in PAIRS: 8 gathers in flight before first consume
// (halves exposed load latency; temps kept < 64 VGPR to hold wave capacity).
// ---------------------------------------------------------------------------
__global__ __launch_bounds__(256) void main_kernel(
    const float* __restrict__ srcT,   // (N*B, HW, 32) channels-last
    const float* __restrict__ refT,   // (B,   HW, 32) channels-last
    const float* __restrict__ depth,  // (B, D, H, W) original layout
    const float* __restrict__ mats,   // (B*N, 12) rot row-major + trans
    const float* __restrict__ regw,   // (8,)
    const float* __restrict__ regb,   // (1,)
    float* __restrict__ out)          // [B*HW depth][B*D*HW attn]
{
    int tid = threadIdx.x;
    int g  = tid & 7;
    int d  = tid >> 3;      // 0..31

    int bid = blockIdx.x;
    int p   = (bid & 7) * ((BB * HW) / 8) + (bid >> 3);  // XCD-contiguous band
    int b   = p / HW;
    int rem = p - b * HW;
    int y   = rem / WW;
    int x   = rem - y * WW;

    // this thread's group of the ref feature (one float4)
    float4 R = *(const float4*)(refT + (size_t)p * 32 + g * 4);
    v2f Rlo = { R.x, R.y }, Rhi = { R.z, R.w };
    float rwg = regw[g];
    float rb  = regb[0];

    __shared__ float4 sW[NN][DD + 1];  // bilinear weights per (n,d), padded
    __shared__ int4   sI[NN][DD + 1];  // pre-scaled (*8) tap indices, padded
    __shared__ float  sL[NN][DD + 8];  // per-source logits over depth, padded
    __shared__ float4 sCWT[DD];        // per-depth cw[4 sources] * 0.25
    __shared__ float  sCWS[DD];        // sum over sources of cw + 1e-8
    __shared__ float  sE[DD];          // final logits over depth
    __shared__ float  sDep[DD];        // depth hypothesis per d

    // ---- Phase 0 (waves 0-1 only): one thread per (n0, dd) homography
    if (tid < 128) {
        int n0 = tid & 3;
        int dd = tid >> 2;            // 0..31
        float fx = (float)x, fy = (float)y;
        float depM = depth[((size_t)(b * DD + dd) * HH + y) * WW + x];
        const float* Mp = mats + (size_t)(b * NN + n0) * 12;
        float4 m0 = *(const float4*)(Mp);       // rows are 48B -> 16B aligned
        float4 m1 = *(const float4*)(Mp + 4);
        float4 m2 = *(const float4*)(Mp + 8);
        float ax = m0.x * fx + m0.y * fy + m0.z;
        float ay = m0.w * fx + m1.x * fy + m1.y;
        float az = m1.z * fx + m1.w * fy + m2.x;
        float px = ax * depM + m2.y;
        float py = ay * depM + m2.z;
        float pz = az * depM + m2.w;
        float z  = (pz == 0.f) ? 1e-9f : pz;
        float rz = __builtin_amdgcn_rcpf(z);
        float gx = px * rz, gy = py * rz;

        float x0f = floorf(gx), y0f = floorf(gy);
        float wx = gx - x0f, wy = gy - y0f;
        bool vx0 = (x0f >= 0.f)  && (x0f <= (float)(WW - 1));
        bool vx1 = (x0f >= -1.f) && (x0f <= (float)(WW - 2));
        bool vy0 = (y0f >= 0.f)  && (y0f <= (float)(HH - 1));
        bool vy1 = (y0f >= -1.f) && (y0f <= (float)(HH - 2));
        float W00 = (vx0 && vy0) ? (1.f - wx) * (1.f - wy) : 0.f;
        float W10 = (vx1 && vy0) ? wx * (1.f - wy)         : 0.f;
        float W01 = (vx0 && vy1) ? (1.f - wx) * wy         : 0.f;
        float W11 = (vx1 && vy1) ? wx * wy                 : 0.f;

        int xi0 = (int)fminf(fmaxf(x0f,       0.f), (float)(WW - 1));
        int xi1 = (int)fminf(fmaxf(x0f + 1.f, 0.f), (float)(WW - 1));
        int yi0 = (int)fminf(fmaxf(y0f,       0.f), (float)(HH - 1));
        int yi1 = (int)fminf(fmaxf(y0f + 1.f, 0.f), (float)(HH - 1));

        sW[n0][dd] = make_float4(W00, W10, W01, W11);
        sI[n0][dd] = make_int4((yi0 * WW + xi0) * 8, (yi0 * WW + xi1) * 8,
                               (yi1 * WW + xi0) * 8, (yi1 * WW + xi1) * 8);
        if (n0 == 0) sDep[dd] = depM;
    }
    __syncthreads();   // barrier 0: sW/sI/sDep populated

    float cor[NN];

    // ---- Phase 1: pairwise-batched gathers + packed blend/dot + g-sum
#pragma unroll
    for (int np = 0; np < 2; np++) {
        int na = 2 * np, nb2 = 2 * np + 1;
        float4 wv0 = sW[na][d];
        int4   iv0 = sI[na][d];
        float4 wv1 = sW[nb2][d];
        int4   iv1 = sI[nb2][d];

        const float4* S0 = (const float4*)(srcT + (size_t)(na  * BB + b) * (32 * HW)) + g;
        const float4* S1 = (const float4*)(srcT + (size_t)(nb2 * BB + b) * (32 * HW)) + g;
        // batch both sources' 8 gathers before any consume
        float4 a0 = S0[iv0.x];
        float4 b0 = S0[iv0.y];
        float4 c0 = S0[iv0.z];
        float4 e0 = S0[iv0.w];
        float4 a1 = S1[iv1.x];
        float4 b1 = S1[iv1.y];
        float4 c1 = S1[iv1.z];
        float4 e1 = S1[iv1.w];

        // consume source na
        {
            v2f alo = { a0.x, a0.y }, ahi = { a0.z, a0.w };
            v2f blo = { b0.x, b0.y }, bhi = { b0.z, b0.w };
            v2f clo = { c0.x, c0.y }, chi = { c0.z, c0.w };
            v2f elo = { e0.x, e0.y }, ehi = { e0.z, e0.w };
            v2f wlo = wv0.x * alo + wv0.y * blo + wv0.z * clo + wv0.w * elo;
            v2f whi = wv0.x * ahi + wv0.y * bhi + wv0.z * chi + wv0.w * ehi;
            v2f pr  = wlo * Rlo + whi * Rhi;
            float cr = pr.x + pr.y;
            cor[na] = cr;
            float ls = cr;
            ls += __shfl_xor(ls, 1);
            ls += __shfl_xor(ls, 2);
            ls += __shfl_xor(ls, 4);
            if (g == 0) sL[na][d] = ls * 0.125f;
        }
        // consume source nb2
        {
            v2f alo = { a1.x, a1.y }, ahi = { a1.z, a1.w };
            v2f blo = { b1.x, b1.y }, bhi = { b1.z, b1.w };
            v2f clo = { c1.x, c1.y }, chi = { c1.z, c1.w };
            v2f elo = { e1.x, e1.y }, ehi = { e1.z, e1.w };
            v2f wlo = wv1.x * alo + wv1.y * blo + wv1.z * clo + wv1.w * elo;
            v2f whi = wv1.x * ahi + wv1.y * bhi + wv1.z * chi + wv1.w * ehi;
            v2f pr  = wlo * Rlo + whi * Rhi;
            float cr = pr.x + pr.y;
            cor[nb2] = cr;
            float ls = cr;
            ls += __shfl_xor(ls, 1);
            ls += __shfl_xor(ls, 2);
            ls += __shfl_xor(ls, 4);
            if (g == 0) sL[nb2][d] = ls * 0.125f;
        }
    }
    __syncthreads();   // barrier 1: sL fully populated

    // ---- Stats: wave 0 computes cw tables for all n,d
    if (tid < 64) {
        int n  = tid >> 4;       // 0..3
        int dh = tid & 15;       // 0..15; covers d=dh and d=dh+16
        float l0 = sL[n][dh];
        float l1 = sL[n][dh + 16];
        float m = fmaxf(l0, l1);
        m = fmaxf(m, __shfl_xor(m, 1));
        m = fmaxf(m, __shfl_xor(m, 2));
        m = fmaxf(m, __shfl_xor(m, 4));
        m = fmaxf(m, __shfl_xor(m, 8));
        float e0 = __expf(l0 - m), e1 = __expf(l1 - m);
        float s = e0 + e1;
        s += __shfl_xor(s, 1);
        s += __shfl_xor(s, 2);
        s += __shfl_xor(s, 4);
        s += __shfl_xor(s, 8);
        float f = 0.17677669529663687f / s;   // fold 1/sqrt(C=32)
        float c0 = e0 * f, c1 = e1 * f;
        // transposed, 0.25 (mean over C//G=4) pre-folded for phase 2's b128 read
        ((float*)&sCWT[dh])[n]      = c0 * 0.25f;
        ((float*)&sCWT[dh + 16])[n] = c1 * 0.25f;
        // cross-source sum per depth (lanes with same dh across the 4 n-groups)
        float t0 = c0, t1 = c1;
        t0 += __shfl_xor(t0, 16); t0 += __shfl_xor(t0, 32);
        t1 += __shfl_xor(t1, 16); t1 += __shfl_xor(t1, 32);
        if (n == 0) {
            sCWS[dh]      = t0 + 1e-8f;
            sCWS[dh + 16] = t1 + 1e-8f;
        }
    }
    __syncthreads();   // barrier 2: sCWT/sCWS ready

    // ---- Phase 2: per-thread weighted accumulation + reg projection
    float4 cwv = sCWT[d];
    float cf = cwv.x * cor[0] + cwv.y * cor[1] + cwv.z * cor[2] + cwv.w * cor[3];
    float v = cf * rwg;
    v += __shfl_xor(v, 1);
    v += __shfl_xor(v, 2);
    v += __shfl_xor(v, 4);
    float logit2 = v * __builtin_amdgcn_rcpf(sCWS[d]) + rb;  // same across octet
    if (g == 0) sE[d] = logit2;
    __syncthreads();   // barrier 3: sE fully populated

    // ---- Final: wave 0 alone — softmax over D, attn writes, argmax depth
    if (tid < 64) {
        int dl = tid & 31;               // both wave halves compute identically
        float q = sE[dl];
        float m2 = q;
        m2 = fmaxf(m2, __shfl_xor(m2, 1));
        m2 = fmaxf(m2, __shfl_xor(m2, 2));
        m2 = fmaxf(m2, __shfl_xor(m2, 4));
        m2 = fmaxf(m2, __shfl_xor(m2, 8));
        m2 = fmaxf(m2, __shfl_xor(m2, 16));
        float e2 = __expf(q - m2);
        float t2 = e2;
        t2 += __shfl_xor(t2, 1);
        t2 += __shfl_xor(t2, 2);
        t2 += __shfl_xor(t2, 4);
        t2 += __shfl_xor(t2, 8);
        t2 += __shfl_xor(t2, 16);
        float aw = e2 / t2;
        if (tid < 32)
            out[(size_t)BB * HW + (size_t)(b * DD + dl) * HW + rem] = aw;

        // argmax over D (first-max semantics), within each 32-lane half
        float bv = q; int bi = dl;
#pragma unroll
        for (int s = 1; s <= 16; s <<= 1) {
            float ov = __shfl_xor(bv, s);
            int   oi = __shfl_xor(bi, s);
            if (ov > bv || (ov == bv && oi < bi)) { bv = ov; bi = oi; }
        }
        if (tid < 32 && dl == bi) out[p] = sDep[bi];
    }
}

// ---------------------------------------------------------------------------
extern "C" void kernel_launch(void* const* d_in, const int* in_sizes, int n_in,
                              void* d_out, int out_size, void* d_ws, size_t ws_size,
                              hipStream_t stream) {
    const float* ref   = (const float*)d_in[0];  // (B,C,H,W)
    const float* src   = (const float*)d_in[1];  // (N,B,C,H,W)
    const float* proj  = (const float*)d_in[2];  // (B,N+1,2,4,4)
    const float* depth = (const float*)d_in[3];  // (B,D,H,W)
    const float* regw  = (const float*)d_in[4];  // (8,)
    const float* regb  = (const float*)d_in[5];  // (1,)
    float* out = (float*)d_out;

    float* ws   = (float*)d_ws;
    float* mats = ws;                                 // 96 floats (pad to 256)
    float* srcT = ws + 256;                           // N*B*HW*32 = 5,242,880
    float* refT = srcT + (size_t)NN * BB * HW * 32;   // B*HW*32 = 1,310,720

    prep_transpose<<<dim3(HW / 32, 10), 256, 0, stream>>>(src, ref, proj,
                                                          srcT, refT, mats);
    main_kernel<<<BB * HW, 256, 0, stream>>>(srcT, refT, depth, mats,
                                             regw, regb, out);
}